// Round 6
// baseline (352.882 us; speedup 1.0000x reference)
//
#include <hip/hip_runtime.h>

typedef unsigned short u16;
typedef float f32x4 __attribute__((ext_vector_type(4)));
typedef int   i32x4 __attribute__((ext_vector_type(4)));
typedef u16   u16x8 __attribute__((ext_vector_type(8)));

// XOR-swizzle on u16 index within a 128x32 tile: flips 16B-slot bits 3..4
// with ((row>>1)&3). Read passes (16 lanes, same lg, rows r..r+15) and write
// passes both hit every bank exactly twice (structural minimum).
#define SWZ(i) ((i) ^ ((((i) >> 6) & 3) << 3))

__device__ __forceinline__ u16 f2bf(float f) {
  unsigned u = __float_as_uint(f);
  u += 0x7FFFu + ((u >> 16) & 1u);
  return (u16)(u >> 16);
}

__device__ __forceinline__ int cvt_pk_bf16(float lo, float hi) {
  int r;
  asm("v_cvt_pk_bf16_f32 %0, %1, %2" : "=v"(r) : "v"(lo), "v"(hi));
  return r;
}

__device__ __forceinline__ float tanh_fast(float x) {
  float e = __expf(2.0f * x);
  return 1.0f - 2.0f / (e + 1.0f);
}

__device__ __forceinline__ void mfma_bf16(f32x4& acc, i32x4 a, i32x4 b) {
  asm("v_mfma_f32_16x16x32_bf16 %0, %1, %2, %0" : "+v"(acc) : "v"(a), "v"(b));
}

// ---------------- fp32 -> bf16 cast for the two weight matrices -----------
__global__ __launch_bounds__(256) void wcast_kernel(
    const float* __restrict__ w2, const float* __restrict__ w1,
    u16* __restrict__ w2b, u16* __restrict__ w1b) {
  int i = blockIdx.x * 256 + threadIdx.x;   // 262144 chunks of 8
  const float* src; u16* dst; int j;
  if (i < 131072) { src = w2; dst = w2b; j = i; }
  else            { src = w1; dst = w1b; j = i - 131072; }
  const float4* s = (const float4*)src;
  float4 a = s[2 * j], b = s[2 * j + 1];
  u16x8 o;
  o[0] = f2bf(a.x); o[1] = f2bf(a.y); o[2] = f2bf(a.z); o[3] = f2bf(a.w);
  o[4] = f2bf(b.x); o[5] = f2bf(b.y); o[6] = f2bf(b.z); o[7] = f2bf(b.w);
  *(u16x8*)(dst + (size_t)8 * j) = o;
}

// ---------------- fused GEMM + tanh + weighted reduce over e --------------
// sv[m] = sum_n tanh( sum_k X[m,k] * W[n,k] ) * wv[n]
// X read as fp32, converted to bf16 in-register (no separate cast pass).
// BM=128 rows/block; block covers N-range [split*256, +256) as 2 n-tiles.
// K=1024, BK=32. 4 waves in 2x2. XCD-aware mapping: the 4 splits of each
// mt share an XCD (bx%8) so X rows are fetched ~once per XCD L2.
__global__ __launch_bounds__(256) void score_kernel(
    const float* __restrict__ audio, const u16* __restrict__ w1b,
    const float* __restrict__ wva, float* __restrict__ sva,
    const float* __restrict__ text, const u16* __restrict__ w2b,
    const float* __restrict__ wvt, float* __restrict__ svt) {
  __shared__ u16 At[128 * 32];
  __shared__ u16 Bt[128 * 32];

  int bx = blockIdx.x;
  const float* Xf; const u16* Wb_; const float* wv; float* svout; int mt, split, M;
  if (bx < 256) {
    Xf = audio; Wb_ = w1b; wv = wva; svout = sva; M = 8192;
    mt = (bx & 7) * 8 + (bx >> 5); split = (bx >> 3) & 3;
  } else {
    int x = bx - 256;
    Xf = text; Wb_ = w2b; wv = wvt; svout = svt; M = 16384;
    mt = (x & 7) * 16 + (x >> 5); split = (x >> 3) & 3;
  }

  const int t = threadIdx.x;
  const int wid = t >> 6, lane = t & 63;
  const int wm = wid >> 1, wn = wid & 1;
  const int lane15 = lane & 15, lg = lane >> 4;
  const size_t m_base = (size_t)mt * 128;

  float rs[4][4];
  #pragma unroll
  for (int mi = 0; mi < 4; ++mi)
    #pragma unroll
    for (int r = 0; r < 4; ++r) rs[mi][r] = 0.f;

  // staging: 512 chunks of 8 elems; thread t does chunks t and 256+t.
  const int ar0 = t >> 2,        ac0 = (t & 3) * 8;         // rows 0..63
  const int ar1 = (256 + t) >> 2, ac1 = (t & 3) * 8;        // rows 64..127
  const int wiA0 = SWZ(ar0 * 32 + ac0), wiA1 = SWZ(ar1 * 32 + ac1);

  const float* Xb = Xf + m_base * 1024;

  for (int nt = 0; nt < 2; ++nt) {
    const int n0 = split * 256 + nt * 128;

    f32x4 acc[4][4];
    #pragma unroll
    for (int mi = 0; mi < 4; ++mi)
      #pragma unroll
      for (int ni = 0; ni < 4; ++ni)
        acc[mi][ni] = (f32x4){0.f, 0.f, 0.f, 0.f};

    const u16* Wp = Wb_ + (size_t)n0 * 1024;

    float4 xa0 = *(const float4*)(Xb + (size_t)ar0 * 1024 + ac0);
    float4 xa0b = *(const float4*)(Xb + (size_t)ar0 * 1024 + ac0 + 4);
    float4 xa1 = *(const float4*)(Xb + (size_t)ar1 * 1024 + ac1);
    float4 xa1b = *(const float4*)(Xb + (size_t)ar1 * 1024 + ac1 + 4);
    i32x4 rb0 = *(const i32x4*)(Wp + (size_t)ar0 * 1024 + ac0);
    i32x4 rb1 = *(const i32x4*)(Wp + (size_t)ar1 * 1024 + ac1);

    for (int kt = 0; kt < 32; ++kt) {
      i32x4 wa0, wa1;
      wa0[0] = cvt_pk_bf16(xa0.x, xa0.y);  wa0[1] = cvt_pk_bf16(xa0.z, xa0.w);
      wa0[2] = cvt_pk_bf16(xa0b.x, xa0b.y); wa0[3] = cvt_pk_bf16(xa0b.z, xa0b.w);
      wa1[0] = cvt_pk_bf16(xa1.x, xa1.y);  wa1[1] = cvt_pk_bf16(xa1.z, xa1.w);
      wa1[2] = cvt_pk_bf16(xa1b.x, xa1b.y); wa1[3] = cvt_pk_bf16(xa1b.z, xa1b.w);
      __syncthreads();                 // previous iteration's ds_reads done
      *(i32x4*)(At + wiA0) = wa0;
      *(i32x4*)(At + wiA1) = wa1;
      *(i32x4*)(Bt + wiA0) = rb0;
      *(i32x4*)(Bt + wiA1) = rb1;
      __syncthreads();                 // tiles ready
      if (kt < 31) {                   // prefetch next k-tile into regs
        const int k1 = (kt + 1) * 32;
        xa0  = *(const float4*)(Xb + (size_t)ar0 * 1024 + k1 + ac0);
        xa0b = *(const float4*)(Xb + (size_t)ar0 * 1024 + k1 + ac0 + 4);
        xa1  = *(const float4*)(Xb + (size_t)ar1 * 1024 + k1 + ac1);
        xa1b = *(const float4*)(Xb + (size_t)ar1 * 1024 + k1 + ac1 + 4);
        rb0  = *(const i32x4*)(Wp + (size_t)ar0 * 1024 + k1 + ac0);
        rb1  = *(const i32x4*)(Wp + (size_t)ar1 * 1024 + k1 + ac1);
      }
      i32x4 af[4], bfr[4];
      #pragma unroll
      for (int mi = 0; mi < 4; ++mi) {
        int rr = wm * 64 + mi * 16 + lane15;
        af[mi] = *(const i32x4*)(At + SWZ(rr * 32 + lg * 8));
      }
      #pragma unroll
      for (int ni = 0; ni < 4; ++ni) {
        int rr = wn * 64 + ni * 16 + lane15;
        bfr[ni] = *(const i32x4*)(Bt + SWZ(rr * 32 + lg * 8));
      }
      #pragma unroll
      for (int mi = 0; mi < 4; ++mi)
        #pragma unroll
        for (int ni = 0; ni < 4; ++ni)
          mfma_bf16(acc[mi][ni], af[mi], bfr[ni]);
    }

    // epilogue: fold tanh(C[m,n]) * wv[n] into per-row partials.
    // C/D layout (m89-verified): col = lane&15, row = (lane>>4)*4 + reg
    float wvn[4];
    #pragma unroll
    for (int ni = 0; ni < 4; ++ni) wvn[ni] = wv[n0 + wn * 64 + ni * 16 + lane15];
    #pragma unroll
    for (int mi = 0; mi < 4; ++mi)
      #pragma unroll
      for (int ni = 0; ni < 4; ++ni)
        #pragma unroll
        for (int r = 0; r < 4; ++r)
          rs[mi][r] += tanh_fast(acc[mi][ni][r]) * wvn[ni];
  }

  // reduce over the 16 column-lanes, combine the two wn halves via LDS
  __syncthreads();
  float* sred = (float*)At;
  #pragma unroll
  for (int mi = 0; mi < 4; ++mi)
    #pragma unroll
    for (int r = 0; r < 4; ++r) {
      float v = rs[mi][r];
      v += __shfl_xor(v, 1);
      v += __shfl_xor(v, 2);
      v += __shfl_xor(v, 4);
      v += __shfl_xor(v, 8);
      if (lane15 == 0) sred[wn * 128 + wm * 64 + mi * 16 + lg * 4 + r] = v;
    }
  __syncthreads();
  if (t < 128) svout[(size_t)split * M + m_base + t] = sred[t] + sred[128 + t];
}

// ------ softmax over a + q-chunk + broadcast q-chunk into output rows ------
// grid: 0..255 audio (b=bx>>4, dch=bx&15) -> out half 1; 256..511 text -> half 0.
__global__ __launch_bounds__(256) void softq_bcast_kernel(
    const float* __restrict__ xA, const float* __restrict__ svA,
    const float* __restrict__ xT, const float* __restrict__ svT,
    float* __restrict__ out) {
  int bx = blockIdx.x;
  int stage = bx >> 8;                  // 0 = audio branch, 1 = text branch
  int b = (bx >> 4) & 15, dch = bx & 15;
  int Acnt = stage ? 1024 : 512;
  int M = stage ? 16384 : 8192;
  const float* x = stage ? xT : xA;
  const float* svp = stage ? svT : svA;
  int rowbase = b * Acnt;

  __shared__ float p[1024];
  __shared__ float red[256];
  __shared__ float chunk[64];
  int t = threadIdx.x;

  float mloc = -1e30f;
  for (int a = t; a < Acnt; a += 256) {
    float v = svp[rowbase + a] + svp[M + rowbase + a] +
              svp[2 * M + rowbase + a] + svp[3 * M + rowbase + a];
    p[a] = v;
    mloc = fmaxf(mloc, v);
  }
  #pragma unroll
  for (int off = 32; off; off >>= 1) mloc = fmaxf(mloc, __shfl_xor(mloc, off));
  if ((t & 63) == 0) red[t >> 6] = mloc;
  __syncthreads();
  float mx = fmaxf(fmaxf(red[0], red[1]), fmaxf(red[2], red[3]));

  float sloc = 0.f;
  for (int a = t; a < Acnt; a += 256) {
    float e = __expf(p[a] - mx);
    p[a] = e;
    sloc += e;
  }
  #pragma unroll
  for (int off = 32; off; off >>= 1) sloc += __shfl_xor(sloc, off);
  __syncthreads();
  if ((t & 63) == 0) red[t >> 6] = sloc;
  __syncthreads();
  float inv = 1.0f / (red[0] + red[1] + red[2] + red[3]);

  int dl = t & 63, ag = t >> 6;
  const float* xb = x + (size_t)rowbase * 1024 + dch * 64 + dl;
  float acc = 0.f;
  #pragma unroll 8
  for (int a = ag; a < Acnt; a += 4) acc += p[a] * xb[(size_t)a * 1024];
  __syncthreads();
  red[t] = acc;
  __syncthreads();
  if (t < 64) {
    float tot = red[t] + red[t + 64] + red[t + 128] + red[t + 192];
    chunk[t] = tot * inv;
  }
  __syncthreads();

  // broadcast this 64-float chunk across all L=1024 rows of the output.
  // out halves: [0] att_text (stage 1), [1] att_audio (stage 0).
  size_t base4 = ((stage ? (size_t)0 : (size_t)16777216) +
                  (size_t)b * 1048576 + (size_t)dch * 64) >> 2;
  f32x4* o4 = (f32x4*)out;
  f32x4 v = ((f32x4*)chunk)[t & 15];
  int q = t & 15;
  #pragma unroll 4
  for (int l = t >> 4; l < 1024; l += 16)
    __builtin_nontemporal_store(v, &o4[base4 + (size_t)l * 256 + q]);
}

extern "C" void kernel_launch(void* const* d_in, const int* in_sizes, int n_in,
                              void* d_out, int out_size, void* d_ws, size_t ws_size,
                              hipStream_t stream) {
  const float* text  = (const float*)d_in[0];   // (16,1024,1024)
  const float* audio = (const float*)d_in[1];   // (16, 512,1024)
  const float* Wa1   = (const float*)d_in[4];   // (1024,1024)
  const float* watt1 = (const float*)d_in[5];   // (2048,)
  const float* Wt2   = (const float*)d_in[7];   // (1024,1024)
  const float* watt2 = (const float*)d_in[10];  // (2048,)

  char* ws = (char*)d_ws;
  u16*   w2b = (u16*)(ws);                      // Wt2 bf16   2,097,152 B
  u16*   w1b = (u16*)(ws + 2097152);            // Wa1 bf16   2,097,152 B
  float* sv2 = (float*)(ws + 4194304);          // [4][16384]   262,144 B
  float* sv1 = (float*)(ws + 4456448);          // [4][ 8192]   131,072 B

  wcast_kernel<<<1024, 256, 0, stream>>>(Wt2, Wa1, w2b, w1b);

  score_kernel<<<768, 256, 0, stream>>>(audio, w1b, watt1 + 1024, sv1,
                                        text, w2b, watt2 + 1024, sv2);

  softq_bcast_kernel<<<512, 256, 0, stream>>>(audio, sv1, text, sv2, (float*)d_out);
}